// Round 3
// baseline (65.251 us; speedup 1.0000x reference)
//
#include <hip/hip_runtime.h>
#include <math.h>

#define NVIEWS 4
#define DIM 2048
#define CLAMP_MIN_F 0.0005f
#define CLAMP_MAX_F 0.9995f
#define NORM_EPS_F 1e-12f

// Round-1 structure (1 wave per chunk, 4 waves/block, 1024 blocks = 16
// waves/CU) + fused last-block final reduction (saves the 2nd kernel launch
// and inter-kernel gap). Counter in d_ws is zeroed per call by memsetAsync.
__global__ __launch_bounds__(256, 4) void fused_loss_kernel(
    const float* __restrict__ x, float* __restrict__ partials,
    unsigned int* __restrict__ counter, float* __restrict__ out,
    int C, int nblocks)
{
    const int lane  = threadIdx.x & 63;
    const int wave  = threadIdx.x >> 6;
    const int chunk = blockIdx.x * 4 + wave;

    // acc index map: 0:(0,0) 1:(0,1) 2:(0,2) 3:(0,3) 4:(1,1) 5:(1,2)
    //                6:(1,3) 7:(2,2) 8:(2,3) 9:(3,3)
    float acc[10];
#pragma unroll
    for (int p = 0; p < 10; ++p) acc[p] = 0.0f;

    if (chunk < C) {
        const float* base = x + (size_t)chunk * (NVIEWS * DIM);
#pragma unroll
        for (int it = 0; it < DIM / 256; ++it) {   // 8 iterations
            const int off = it * 256 + lane * 4;
            float rr[4][4];
#pragma unroll
            for (int i = 0; i < 4; ++i)
                *reinterpret_cast<float4*>(rr[i]) =
                    *reinterpret_cast<const float4*>(base + i * DIM + off);
            int p = 0;
#pragma unroll
            for (int i = 0; i < 4; ++i) {
#pragma unroll
                for (int j = i; j < 4; ++j, ++p) {
#pragma unroll
                    for (int k = 0; k < 4; ++k)
                        acc[p] = fmaf(rr[i][k], rr[j][k], acc[p]);
                }
            }
        }
    }

    // wave-level butterfly reduction across 64 lanes
#pragma unroll
    for (int p = 0; p < 10; ++p) {
#pragma unroll
        for (int s = 32; s > 0; s >>= 1)
            acc[p] += __shfl_xor(acc[p], s, 64);
    }

    __shared__ float lds[4];
    float loss = 0.0f;
    if (lane == 0) {
        if (chunk < C) {
            const float n0 = fmaxf(sqrtf(acc[0]), NORM_EPS_F);
            const float n1 = fmaxf(sqrtf(acc[4]), NORM_EPS_F);
            const float n2 = fmaxf(sqrtf(acc[7]), NORM_EPS_F);
            const float n3 = fmaxf(sqrtf(acc[9]), NORM_EPS_F);
            const float i0 = 1.0f / n0, i1 = 1.0f / n1;
            const float i2 = 1.0f / n2, i3 = 1.0f / n3;
            float sum = 0.0f, s;
#define TERM(P, IA, IB, W)                                        \
            s = acc[P] * (IA) * (IB);                             \
            s = fminf(fmaxf(s, CLAMP_MIN_F), CLAMP_MAX_F);        \
            sum += (W) * (-__logf(1.0f - s));
            TERM(0, i0, i0, 1.0f)   // diagonal
            TERM(4, i1, i1, 1.0f)
            TERM(7, i2, i2, 1.0f)
            TERM(9, i3, i3, 1.0f)
            TERM(1, i0, i1, 2.0f)   // off-diagonal pairs, counted twice
            TERM(2, i0, i2, 2.0f)
            TERM(3, i0, i3, 2.0f)
            TERM(5, i1, i2, 2.0f)
            TERM(6, i1, i3, 2.0f)
            TERM(8, i2, i3, 2.0f)
#undef TERM
            loss = sum * (1.0f / 16.0f);
        }
        lds[wave] = loss;
    }
    __syncthreads();

    // publish block partial, then last arriving block does the final sum
    __shared__ bool am_last;
    if (threadIdx.x == 0) {
        partials[blockIdx.x] = lds[0] + lds[1] + lds[2] + lds[3];
        __threadfence();                         // release partials
        unsigned int old = atomicAdd(counter, 1u);
        am_last = (old == (unsigned int)(nblocks - 1));
    }
    __syncthreads();

    if (am_last) {
        __threadfence();                         // acquire partials
        float s = 0.0f;
        for (int i = threadIdx.x; i < nblocks; i += 256) s += partials[i];
#pragma unroll
        for (int d = 32; d > 0; d >>= 1) s += __shfl_xor(s, d, 64);
        __shared__ float lds2[4];
        if (lane == 0) lds2[wave] = s;
        __syncthreads();
        if (threadIdx.x == 0) out[0] = lds2[0] + lds2[1] + lds2[2] + lds2[3];
    }
}

extern "C" void kernel_launch(void* const* d_in, const int* in_sizes, int n_in,
                              void* d_out, int out_size, void* d_ws, size_t ws_size,
                              hipStream_t stream)
{
    const float* x = (const float*)d_in[0];
    float* out = (float*)d_out;
    float* partials = (float*)d_ws;                       // nblocks floats
    unsigned int* counter = (unsigned int*)((char*)d_ws + 8192);

    const int total  = in_sizes[0];
    const int C      = total / (NVIEWS * DIM);   // 4096 chunks
    const int blocks = (C + 3) / 4;              // 1024 blocks

    // counter must be zero at kernel start on EVERY call (ws is poisoned
    // once, never re-poisoned) — memset node is graph-capturable.
    hipMemsetAsync(counter, 0, sizeof(unsigned int), stream);
    fused_loss_kernel<<<blocks, 256, 0, stream>>>(x, partials, counter, out, C, blocks);
}

// Round 4
// 30.794 us; speedup vs baseline: 2.1190x; 2.1190x over previous
//
#include <hip/hip_runtime.h>
#include <math.h>

#define NVIEWS 4
#define DIM 2048
#define CLAMP_MIN_F 0.0005f
#define CLAMP_MAX_F 0.9995f
#define NORM_EPS_F 1e-12f

// One wave (64 lanes) per chunk of 4 rows, 4 waves/block, 1024 blocks
// (= 4 blocks/CU, 16 waves/CU). Manual double-buffered float4 loads: 8
// outstanding 1-KiB loads per wave while FMAs run on the previous set.
// Two-kernel structure on purpose: last-block atomic fusion measured 102 us
// (same-address device-scope atomics serialize ~80ns apiece on CDNA4).
__global__ __launch_bounds__(256, 4) void chunk_loss_kernel(
    const float* __restrict__ x, float* __restrict__ partials, int C)
{
    const int lane  = threadIdx.x & 63;
    const int wave  = threadIdx.x >> 6;
    const int chunk = blockIdx.x * 4 + wave;

    // acc index map: 0:(0,0) 1:(0,1) 2:(0,2) 3:(0,3) 4:(1,1) 5:(1,2)
    //                6:(1,3) 7:(2,2) 8:(2,3) 9:(3,3)
    float acc[10];
#pragma unroll
    for (int p = 0; p < 10; ++p) acc[p] = 0.0f;

    if (chunk < C) {
        const float* base = x + (size_t)chunk * (NVIEWS * DIM) + lane * 4;
        float cur[4][4], nxt[4][4];
#pragma unroll
        for (int i = 0; i < 4; ++i)
            *reinterpret_cast<float4*>(cur[i]) =
                *reinterpret_cast<const float4*>(base + i * DIM);

#pragma unroll
        for (int it = 0; it < DIM / 256 - 1; ++it) {   // 7 pipelined iters
            const int noff = (it + 1) * 256;
#pragma unroll
            for (int i = 0; i < 4; ++i)
                *reinterpret_cast<float4*>(nxt[i]) =
                    *reinterpret_cast<const float4*>(base + i * DIM + noff);
            int p = 0;
#pragma unroll
            for (int i = 0; i < 4; ++i)
#pragma unroll
                for (int j = i; j < 4; ++j, ++p)
#pragma unroll
                    for (int k = 0; k < 4; ++k)
                        acc[p] = fmaf(cur[i][k], cur[j][k], acc[p]);
#pragma unroll
            for (int i = 0; i < 4; ++i)
#pragma unroll
                for (int k = 0; k < 4; ++k)
                    cur[i][k] = nxt[i][k];   // unrolled -> register renaming
        }
        int p = 0;
#pragma unroll
        for (int i = 0; i < 4; ++i)
#pragma unroll
            for (int j = i; j < 4; ++j, ++p)
#pragma unroll
                for (int k = 0; k < 4; ++k)
                    acc[p] = fmaf(cur[i][k], cur[j][k], acc[p]);
    }

    // wave-level butterfly reduction across 64 lanes
#pragma unroll
    for (int p = 0; p < 10; ++p) {
#pragma unroll
        for (int s = 32; s > 0; s >>= 1)
            acc[p] += __shfl_xor(acc[p], s, 64);
    }

    __shared__ float lds[4];
    float loss = 0.0f;
    if (lane == 0) {
        if (chunk < C) {
            const float n0 = fmaxf(sqrtf(acc[0]), NORM_EPS_F);
            const float n1 = fmaxf(sqrtf(acc[4]), NORM_EPS_F);
            const float n2 = fmaxf(sqrtf(acc[7]), NORM_EPS_F);
            const float n3 = fmaxf(sqrtf(acc[9]), NORM_EPS_F);
            const float i0 = 1.0f / n0, i1 = 1.0f / n1;
            const float i2 = 1.0f / n2, i3 = 1.0f / n3;
            float sum = 0.0f, s;
#define TERM(P, IA, IB, W)                                        \
            s = acc[P] * (IA) * (IB);                             \
            s = fminf(fmaxf(s, CLAMP_MIN_F), CLAMP_MAX_F);        \
            sum += (W) * (-__logf(1.0f - s));
            TERM(0, i0, i0, 1.0f)   // diagonal
            TERM(4, i1, i1, 1.0f)
            TERM(7, i2, i2, 1.0f)
            TERM(9, i3, i3, 1.0f)
            TERM(1, i0, i1, 2.0f)   // off-diagonal pairs, counted twice
            TERM(2, i0, i2, 2.0f)
            TERM(3, i0, i3, 2.0f)
            TERM(5, i1, i2, 2.0f)
            TERM(6, i1, i3, 2.0f)
            TERM(8, i2, i3, 2.0f)
#undef TERM
            loss = sum * (1.0f / 16.0f);
        }
        lds[wave] = loss;
    }
    __syncthreads();
    if (threadIdx.x == 0)
        partials[blockIdx.x] = lds[0] + lds[1] + lds[2] + lds[3];
}

// Minimal deterministic final reduction: one wave, float4 loads.
__global__ __launch_bounds__(64) void reduce_kernel(
    const float* __restrict__ partials, float* __restrict__ out, int n)
{
    float s = 0.0f;
    for (int i = threadIdx.x * 4; i < n; i += 64 * 4) {
        const float4 v = *reinterpret_cast<const float4*>(partials + i);
        s += (v.x + v.y) + (v.z + v.w);
    }
#pragma unroll
    for (int d = 32; d > 0; d >>= 1) s += __shfl_xor(s, d, 64);
    if (threadIdx.x == 0) out[0] = s;
}

extern "C" void kernel_launch(void* const* d_in, const int* in_sizes, int n_in,
                              void* d_out, int out_size, void* d_ws, size_t ws_size,
                              hipStream_t stream)
{
    const float* x = (const float*)d_in[0];
    float* out = (float*)d_out;
    float* partials = (float*)d_ws;   // nblocks floats (4 KiB)

    const int total  = in_sizes[0];
    const int C      = total / (NVIEWS * DIM);   // 4096 chunks
    const int blocks = (C + 3) / 4;              // 1024 blocks

    chunk_loss_kernel<<<blocks, 256, 0, stream>>>(x, partials, C);
    reduce_kernel<<<1, 64, 0, stream>>>(partials, out, blocks);
}